// Round 7
// baseline (122.350 us; speedup 1.0000x reference)
//
#include <hip/hip_runtime.h>

#define EPS 1e-8f

typedef float f32x4 __attribute__((ext_vector_type(4)));

// ---------------------------------------------------------------------------
// Output layout (floats):
//   [0,        65536)      concrete_lower  [64,1024]
//   [65536,    131072)     concrete_upper  [64,1024]
//   [131072,   67239936)   lower_coef      [64,1024,1024] (diag only)
//   [67239936, 134348800)  upper_coef      [64,1024,1024] (diag only)
//   [134348800,134414336)  lower_bias      [64,1024] (zeros)
//   [134414336,134479872)  upper_bias      [64,1024] (mu_upper)
//
// Single fused kernel. Work unit = one 1024-float "virtual row" (4 KB),
// written by one wave as 4 x (64-lane float4) stores. Virtual rows:
//   vr in [0, 131072)       coef rows (lower_coef then upper_coef, both at
//                           out + 131072 + vr*1024), diagonal col = vr & 1023
//   vr in [131072, 131136)  lower_bias rows (zeros)
//   vr in [131136, 131200)  concrete_lower rows (max(l,0))
//   vr in [131200, 131264)  concrete_upper rows (max(u,0))
//   vr in [131264, 131328)  upper_bias rows (mu)
// 8192 waves; each owns a contiguous band of 16-17 rows (64-68 KB stream).
// Plain (cached) stores: rocclr's fillBufferAligned sustains 6.55 TB/s with
// plain stores; nt stores peaked at 5.4 TB/s in rounds 4-5.
// ---------------------------------------------------------------------------

__global__ void __launch_bounds__(256)
fused_kernel(const float* __restrict__ lower,
             const float* __restrict__ upper,
             float* __restrict__ out) {
    const int lane = threadIdx.x & 63;
    const int W = blockIdx.x * 4 + (threadIdx.x >> 6);  // global wave id 0..8191
    // Contiguous row band: waves 0..255 get 17 rows, the rest 16.
    const int start = W * 16 + (W < 256 ? W : 256);
    const int count = (W < 256) ? 17 : 16;

    for (int ri = 0; ri < count; ++ri) {
        const int vr = start + ri;
        if (vr < 131072) {
            // ---- coef row (diagonal-only) ----
            const int rr = vr & 65535;           // flat (b,i) into [64,1024]
            const float l = lower[rr];           // wave-uniform address
            const float u = upper[rr];
            const bool active = (l >= 0.0f);
            const bool crossing = (l < 0.0f) && (u > 0.0f);
            const float lam = crossing ? u / (u - l + EPS) : 0.0f;
            // lower_diag: active?1:0 ; upper_diag: active?1:lam
            const float v = active ? 1.0f : (vr < 65536 ? 0.0f : lam);
            const int i = vr & 1023;             // diagonal column
            f32x4* rp = (f32x4*)(out + 131072 + (size_t)vr * 1024) + lane;
            const int base = lane * 4;
#pragma unroll
            for (int k = 0; k < 4; ++k) {
                const int b = base + k * 256;    // first float col of this f4
                f32x4 z;
                z.x = (b + 0 == i) ? v : 0.0f;
                z.y = (b + 1 == i) ? v : 0.0f;
                z.z = (b + 2 == i) ? v : 0.0f;
                z.w = (b + 3 == i) ? v : 0.0f;
                rp[k * 64] = z;
            }
        } else if (vr < 131136) {
            // ---- lower_bias row: zeros ----
            f32x4* rp = (f32x4*)(out + 134348800LL +
                                 (size_t)(vr - 131072) * 1024) + lane;
            const f32x4 z = {0.0f, 0.0f, 0.0f, 0.0f};
#pragma unroll
            for (int k = 0; k < 4; ++k) rp[k * 64] = z;
        } else if (vr < 131200) {
            // ---- concrete_lower row ----
            const int r = vr - 131136;
            const f32x4* lp = (const f32x4*)(lower + (size_t)r * 1024) + lane;
            f32x4* rp = (f32x4*)(out + (size_t)r * 1024) + lane;
#pragma unroll
            for (int k = 0; k < 4; ++k) {
                f32x4 a = lp[k * 64];
                a.x = fmaxf(a.x, 0.0f);
                a.y = fmaxf(a.y, 0.0f);
                a.z = fmaxf(a.z, 0.0f);
                a.w = fmaxf(a.w, 0.0f);
                rp[k * 64] = a;
            }
        } else if (vr < 131264) {
            // ---- concrete_upper row ----
            const int r = vr - 131200;
            const f32x4* up = (const f32x4*)(upper + (size_t)r * 1024) + lane;
            f32x4* rp = (f32x4*)(out + 65536 + (size_t)r * 1024) + lane;
#pragma unroll
            for (int k = 0; k < 4; ++k) {
                f32x4 a = up[k * 64];
                a.x = fmaxf(a.x, 0.0f);
                a.y = fmaxf(a.y, 0.0f);
                a.z = fmaxf(a.z, 0.0f);
                a.w = fmaxf(a.w, 0.0f);
                rp[k * 64] = a;
            }
        } else {
            // ---- upper_bias row: mu ----
            const int r = vr - 131264;
            const f32x4* lp = (const f32x4*)(lower + (size_t)r * 1024) + lane;
            const f32x4* up = (const f32x4*)(upper + (size_t)r * 1024) + lane;
            f32x4* rp = (f32x4*)(out + 134414336LL + (size_t)r * 1024) + lane;
#pragma unroll
            for (int k = 0; k < 4; ++k) {
                f32x4 lv = lp[k * 64];
                f32x4 uv = up[k * 64];
                f32x4 m;
#pragma unroll
                for (int e = 0; e < 4; ++e) {
                    float l = lv[e], u = uv[e];
                    bool crossing = (l < 0.0f) && (u > 0.0f);
                    float lam = crossing ? u / (u - l + EPS) : 0.0f;
                    m[e] = crossing ? -lam * l : 0.0f;
                }
                rp[k * 64] = m;
            }
        }
    }
}

extern "C" void kernel_launch(void* const* d_in, const int* in_sizes, int n_in,
                              void* d_out, int out_size, void* d_ws, size_t ws_size,
                              hipStream_t stream) {
    const float* lower = (const float*)d_in[0];
    const float* upper = (const float*)d_in[1];
    float* out = (float*)d_out;

    // 131328 virtual rows / 8192 waves; one dispatch writes every output.
    fused_kernel<<<2048, 256, 0, stream>>>(lower, upper, out);
}